// Round 5
// baseline (761.437 us; speedup 1.0000x reference)
//
#include <hip/hip_runtime.h>

// VGAE encoder: 3x GCNConv (sym-norm + self loops), relu, relu, none.
// out = concat(mu, logstd=mu)
// Round 5: XCD-slice k_agg (blockIdx%8 = feature slice -> per-XCD L2-resident
// h slice), src-only CSR pairs (coef recomputed from dinv), reg-blocked GEMM.
constexpr int NN = 50000;   // nodes
constexpr int NE = 800000;  // edges

// ---- CSR build: count in-degree at dst -------------------------------------
__global__ void k_count(const int* __restrict__ dst, int* __restrict__ cnt) {
    int e = blockIdx.x * blockDim.x + threadIdx.x;
    if (e < NE) atomicAdd(&cnt[dst[e]], 1);
}

// ---- single-block exclusive scan of counts -> rowptr, cursor; also dinv ----
__global__ void __launch_bounds__(1024) k_scan(const int* __restrict__ cnt,
                                               int* __restrict__ rowptr,
                                               int* __restrict__ cursor,
                                               float* __restrict__ dinv) {
    __shared__ int wexcl[16];
    __shared__ int s_carry;
    __shared__ int s_total;
    int tid = threadIdx.x;
    int lane = tid & 63, wid = tid >> 6;
    if (tid == 0) s_carry = 0;
    __syncthreads();
    for (int base = 0; base < NN; base += 1024) {
        int i = base + tid;
        int v = (i < NN) ? cnt[i] : 0;
        int x = v;  // wave-inclusive scan
#pragma unroll
        for (int off = 1; off < 64; off <<= 1) {
            int t = __shfl_up(x, off);
            if (lane >= off) x += t;
        }
        if (lane == 63) wexcl[wid] = x;  // wave totals
        __syncthreads();
        int carry = s_carry;
        if (wid == 0) {
            int wt = (lane < 16) ? wexcl[lane] : 0;
            int y = wt;
#pragma unroll
            for (int off = 1; off < 16; off <<= 1) {
                int t = __shfl_up(y, off);
                if (lane >= off) y += t;
            }
            if (lane < 16) wexcl[lane] = y - wt;  // exclusive wave offsets
            if (lane == 15) s_total = y;          // tile total
        }
        __syncthreads();
        if (i < NN) {
            int r = carry + wexcl[wid] + (x - v);  // global exclusive prefix
            rowptr[i] = r;
            cursor[i] = r;
            dinv[i] = rsqrtf((float)v + 1.0f);  // +1 self loop
        }
        __syncthreads();
        if (tid == 0) s_carry = carry + s_total;
        __syncthreads();
    }
    if (tid == 0) rowptr[NN] = s_carry;
}

// ---- fill CSR with src indices (coef recomputed later from dinv) -----------
__global__ void k_fill(const int* __restrict__ src, const int* __restrict__ dst,
                       int* __restrict__ cursor, int* __restrict__ srcs) {
    int e = blockIdx.x * blockDim.x + threadIdx.x;
    if (e >= NE) return;
    int s = src[e], d = dst[e];
    int pos = atomicAdd(&cursor[d], 1);
    srcs[pos] = s;
}

// ---- dense H = X @ W, LDS-staged, 4 rows x 2 float4 per thread -------------
template<int FIN, int FOUT>
__global__ void k_gemm(const float* __restrict__ X, const float* __restrict__ W,
                       float* __restrict__ H) {
    constexpr int ROWS = 64, RPT = 4, CPT = 2;
    constexpr int GC = FOUT / 4;       // float4 cols
    constexpr int CG = GC / CPT;       // col groups
    constexpr int RG = ROWS / RPT;     // row groups (16)
    constexpr int NT = RG * CG;        // threads
    __shared__ float sW[FIN * FOUT];
    __shared__ float sX[ROWS * FIN];
    int tid = threadIdx.x;
    int row0 = blockIdx.x * ROWS;
    for (int i = tid; i < FIN * GC; i += NT)
        ((float4*)sW)[i] = ((const float4*)W)[i];
    constexpr int XF4 = ROWS * FIN / 4;
    for (int i = tid; i < XF4; i += NT) {
        int r = i / (FIN / 4);
        int gr = row0 + r;
        ((float4*)sX)[i] = (gr < NN)
            ? ((const float4*)(X + (size_t)gr * FIN))[i % (FIN / 4)]
            : make_float4(0.f, 0.f, 0.f, 0.f);
    }
    __syncthreads();
    int rg = tid / CG, cg = tid % CG;
    int rbase = rg * RPT;
    float4 acc[RPT][CPT] = {};
    for (int k = 0; k < FIN; k += 4) {
        float4 xv[RPT];
#pragma unroll
        for (int i = 0; i < RPT; ++i)
            xv[i] = *(const float4*)&sX[(rbase + i) * FIN + k];
#pragma unroll
        for (int kk = 0; kk < 4; ++kk) {
#pragma unroll
            for (int j = 0; j < CPT; ++j) {
                float4 w4 = ((const float4*)sW)[(k + kk) * GC + cg * CPT + j];
#pragma unroll
                for (int i = 0; i < RPT; ++i) {
                    float xs = (&xv[i].x)[kk];
                    acc[i][j].x += xs * w4.x; acc[i][j].y += xs * w4.y;
                    acc[i][j].z += xs * w4.z; acc[i][j].w += xs * w4.w;
                }
            }
        }
    }
#pragma unroll
    for (int i = 0; i < RPT; ++i) {
        int gr = row0 + rbase + i;
        if (gr < NN)
#pragma unroll
            for (int j = 0; j < CPT; ++j)
                ((float4*)H)[(size_t)gr * GC + cg * CPT + j] = acc[i][j];
    }
}

// ---- gather aggregate + self-loop + bias (+relu | mirror), XCD-sliced ------
// Grid: (tiles * 8); slice = blockIdx&7 owns chunks [slice*CS, slice*CS+CS).
// Per-XCD h-footprint = NN * CS*16 B (2.4MB @96, fits 4MB L2).
// MODE 0: relu, write outp. MODE 1: write outp and mirror to outp+NN*F.
template<int F, int MODE>
__global__ void k_agg(const float* __restrict__ H, const int* __restrict__ rowptr,
                      const int* __restrict__ srcs, const float* __restrict__ dinv,
                      const float* __restrict__ b, float* __restrict__ outp) {
    constexpr int C = F / 4;        // float4 chunks per row
    constexpr int CS = C / 8;       // chunks per slice (3 @96, 2 @64)
    constexpr int RT = 64;          // rows per tile
    int slice = blockIdx.x & 7;
    int tile  = blockIdx.x >> 3;
    int tid = threadIdx.x;          // RT*CS threads
    int n = tile * RT + tid / CS;
    int c = slice * CS + tid % CS;
    if (n >= NN) return;
    int beg = rowptr[n], end = rowptr[n + 1];
    float di = dinv[n];
    const float4* h4 = (const float4*)H;
    float4 hv = h4[(size_t)n * C + c];
    float sl = di * di;
    float4 acc = make_float4(sl * hv.x, sl * hv.y, sl * hv.z, sl * hv.w);
    for (int p = beg; p < end; ++p) {
        int s = srcs[p];
        float coef = dinv[s] * di;
        float4 v = h4[(size_t)s * C + c];
        acc.x += coef * v.x; acc.y += coef * v.y;
        acc.z += coef * v.z; acc.w += coef * v.w;
    }
    float4 bb = *(const float4*)(b + c * 4);
    acc.x += bb.x; acc.y += bb.y; acc.z += bb.z; acc.w += bb.w;
    if (MODE == 0) {
        acc.x = fmaxf(acc.x, 0.f); acc.y = fmaxf(acc.y, 0.f);
        acc.z = fmaxf(acc.z, 0.f); acc.w = fmaxf(acc.w, 0.f);
        ((float4*)outp)[(size_t)n * C + c] = acc;
    } else {
        ((float4*)outp)[(size_t)n * C + c] = acc;
        ((float4*)outp)[(size_t)NN * C + (size_t)n * C + c] = acc;  // logstd = mu
    }
}

extern "C" void kernel_launch(void* const* d_in, const int* in_sizes, int n_in,
                              void* d_out, int out_size, void* d_ws, size_t ws_size,
                              hipStream_t stream) {
    const float* x  = (const float*)d_in[0];
    const int*   ei = (const int*)d_in[1];  // [2, NE] int32
    const float* W0 = (const float*)d_in[2];
    const float* b0 = (const float*)d_in[3];
    const float* W1 = (const float*)d_in[4];
    const float* b1 = (const float*)d_in[5];
    const float* W2 = (const float*)d_in[6];
    const float* b2 = (const float*)d_in[7];
    float* out = (float*)d_out;

    // ws: [cnt 51200][rowptr 51200][cursor 51200][dinv 51200][srcs NE]
    //     [bufH NN*96][bufA NN*96]
    int*   cnt    = (int*)d_ws;
    int*   rowptr = cnt + 51200;
    int*   cursor = rowptr + 51200;
    float* dinv   = (float*)(cursor + 51200);
    int*   srcs   = (int*)(dinv + 51200);
    float* bufH   = (float*)(srcs + NE);
    float* bufA   = bufH + (size_t)NN * 96;

    const int* src = ei;
    const int* dst = ei + NE;

    // CSR build (graph constant across layers; rebuilt identically every call)
    hipMemsetAsync(cnt, 0, NN * sizeof(int), stream);
    k_count<<<NE / 256, 256, 0, stream>>>(dst, cnt);
    k_scan<<<1, 1024, 0, stream>>>(cnt, rowptr, cursor, dinv);
    k_fill<<<NE / 256, 256, 0, stream>>>(src, dst, cursor, srcs);

    constexpr int TILES = (NN + 63) / 64;       // 782
    constexpr int GEMMG = TILES;                // 64 rows per block

    // layer 0: x -> bufA (relu)
    k_gemm<96, 96><<<GEMMG, 192, 0, stream>>>(x, W0, bufH);
    k_agg<96, 0><<<TILES * 8, 192, 0, stream>>>(bufH, rowptr, srcs, dinv, b0, bufA);
    // layer 1: bufA -> bufA (relu)
    k_gemm<96, 96><<<GEMMG, 192, 0, stream>>>(bufA, W1, bufH);
    k_agg<96, 0><<<TILES * 8, 192, 0, stream>>>(bufH, rowptr, srcs, dinv, b1, bufA);
    // layer 2: bufA -> out (mu, mirrored to logstd)
    k_gemm<96, 64><<<GEMMG, 128, 0, stream>>>(bufA, W2, bufH);
    k_agg<64, 1><<<TILES * 8, 128, 0, stream>>>(bufH, rowptr, srcs, dinv, b2, out);
}

// Round 9
// 379.268 us; speedup vs baseline: 2.0077x; 2.0077x over previous
//
#include <hip/hip_runtime.h>

// VGAE encoder: 3x GCNConv (sym-norm + self loops), relu, relu, none.
// out = concat(mu, logstd=mu)
// Round 6: revert XCD slicing (r5 regression: partial-line gathers, 2.85x
// fetch amplification). Round-4 agg layout + (src,coef) pairs + 4x unroll
// for memory-level parallelism. Parallel 3-kernel CSR scan (r4's was 1 block).
constexpr int NN = 50000;   // nodes
constexpr int NE = 800000;  // edges
constexpr int NB = (NN + 1023) / 1024;  // 49 scan blocks

// ---- CSR build: count in-degree at dst -------------------------------------
__global__ void k_count(const int* __restrict__ dst, int* __restrict__ cnt) {
    int e = blockIdx.x * blockDim.x + threadIdx.x;
    if (e < NE) atomicAdd(&cnt[dst[e]], 1);
}

// ---- scan phase A: per-1024-block local exclusive prefix + block sum + dinv -
__global__ void __launch_bounds__(1024) k_scanA(const int* __restrict__ cnt,
                                                int* __restrict__ rowptr,
                                                int* __restrict__ bsum,
                                                float* __restrict__ dinv) {
    __shared__ int wsum[16];
    int tid = threadIdx.x;
    int lane = tid & 63, wid = tid >> 6;
    int i = blockIdx.x * 1024 + tid;
    int v = (i < NN) ? cnt[i] : 0;
    int x = v;
#pragma unroll
    for (int off = 1; off < 64; off <<= 1) {
        int t = __shfl_up(x, off);
        if (lane >= off) x += t;
    }
    if (lane == 63) wsum[wid] = x;
    __syncthreads();
    if (wid == 0) {
        int wt = (lane < 16) ? wsum[lane] : 0;
        int y = wt;
#pragma unroll
        for (int off = 1; off < 16; off <<= 1) {
            int t = __shfl_up(y, off);
            if (lane >= off) y += t;
        }
        if (lane < 16) wsum[lane] = y - wt;   // exclusive wave offsets
        if (lane == 15) bsum[blockIdx.x] = y; // block total
    }
    __syncthreads();
    if (i < NN) {
        rowptr[i] = wsum[wid] + (x - v);      // block-local exclusive prefix
        dinv[i] = rsqrtf((float)v + 1.0f);    // +1 self loop
    }
}

// ---- scan phase B: one wave scans the 49 block sums ------------------------
__global__ void k_scanB(int* __restrict__ bsum, int* __restrict__ boff,
                        int* __restrict__ rowptr) {
    int lane = threadIdx.x;
    int v = (lane < NB) ? bsum[lane] : 0;
    int x = v;
#pragma unroll
    for (int off = 1; off < 64; off <<= 1) {
        int t = __shfl_up(x, off);
        if (lane >= off) x += t;
    }
    if (lane < NB) boff[lane] = x - v;        // exclusive block offsets
    if (lane == NB - 1) rowptr[NN] = x;       // grand total (== NE)
}

// ---- scan phase C: apply block offsets; produce rowptr + cursor ------------
__global__ void k_scanC(int* __restrict__ rowptr, const int* __restrict__ boff,
                        int* __restrict__ cursor) {
    int i = blockIdx.x * blockDim.x + threadIdx.x;
    if (i < NN) {
        int r = rowptr[i] + boff[i >> 10];
        rowptr[i] = r;
        cursor[i] = r;
    }
}

// ---- fill CSR with (src, coef) pairs ---------------------------------------
__global__ void k_fill(const int* __restrict__ src, const int* __restrict__ dst,
                       const float* __restrict__ dinv, int* __restrict__ cursor,
                       int2* __restrict__ pairs) {
    int e = blockIdx.x * blockDim.x + threadIdx.x;
    if (e >= NE) return;
    int s = src[e], d = dst[e];
    int pos = atomicAdd(&cursor[d], 1);
    float coef = dinv[s] * dinv[d];
    pairs[pos] = make_int2(s, __float_as_int(coef));
}

// ---- dense H = X @ W, LDS-staged, 4 rows x 2 float4 per thread -------------
template<int FIN, int FOUT>
__global__ void k_gemm(const float* __restrict__ X, const float* __restrict__ W,
                       float* __restrict__ H) {
    constexpr int ROWS = 64, RPT = 4, CPT = 2;
    constexpr int GC = FOUT / 4;       // float4 cols
    constexpr int CG = GC / CPT;       // col groups
    constexpr int RG = ROWS / RPT;     // row groups (16)
    constexpr int NT = RG * CG;        // threads
    __shared__ float sW[FIN * FOUT];
    __shared__ float sX[ROWS * FIN];
    int tid = threadIdx.x;
    int row0 = blockIdx.x * ROWS;
    for (int i = tid; i < FIN * GC; i += NT)
        ((float4*)sW)[i] = ((const float4*)W)[i];
    constexpr int XF4 = ROWS * FIN / 4;
    for (int i = tid; i < XF4; i += NT) {
        int r = i / (FIN / 4);
        int gr = row0 + r;
        ((float4*)sX)[i] = (gr < NN)
            ? ((const float4*)(X + (size_t)gr * FIN))[i % (FIN / 4)]
            : make_float4(0.f, 0.f, 0.f, 0.f);
    }
    __syncthreads();
    int rg = tid / CG, cg = tid % CG;
    int rbase = rg * RPT;
    float4 acc[RPT][CPT] = {};
    for (int k = 0; k < FIN; k += 4) {
        float4 xv[RPT];
#pragma unroll
        for (int i = 0; i < RPT; ++i)
            xv[i] = *(const float4*)&sX[(rbase + i) * FIN + k];
#pragma unroll
        for (int kk = 0; kk < 4; ++kk) {
#pragma unroll
            for (int j = 0; j < CPT; ++j) {
                float4 w4 = ((const float4*)sW)[(k + kk) * GC + cg * CPT + j];
#pragma unroll
                for (int i = 0; i < RPT; ++i) {
                    float xs = (&xv[i].x)[kk];
                    acc[i][j].x += xs * w4.x; acc[i][j].y += xs * w4.y;
                    acc[i][j].z += xs * w4.z; acc[i][j].w += xs * w4.w;
                }
            }
        }
    }
#pragma unroll
    for (int i = 0; i < RPT; ++i) {
        int gr = row0 + rbase + i;
        if (gr < NN)
#pragma unroll
            for (int j = 0; j < CPT; ++j)
                ((float4*)H)[(size_t)gr * GC + cg * CPT + j] = acc[i][j];
    }
}

// ---- gather aggregate + self-loop + bias (+relu | mirror) ------------------
// One thread per (node, float4-chunk); full rows per block (line-friendly).
// 4x unrolled edge loop: batch pair loads -> batch gathers -> FMAs (MLP).
// MODE 0: relu, write outp. MODE 1: write outp and mirror to outp+NN*F.
template<int F, int MODE>
__global__ void k_agg(const float* __restrict__ H, const int* __restrict__ rowptr,
                      const int2* __restrict__ pairs, const float* __restrict__ dinv,
                      const float* __restrict__ b, float* __restrict__ outp) {
    constexpr int C = F / 4;
    int tid = blockIdx.x * blockDim.x + threadIdx.x;
    int n = tid / C, c = tid % C;
    if (n >= NN) return;
    int beg = rowptr[n], end = rowptr[n + 1];
    float di = dinv[n];
    const float4* h4 = (const float4*)H;
    float4 hv = h4[(size_t)n * C + c];
    float sl = di * di;
    float4 acc = make_float4(sl * hv.x, sl * hv.y, sl * hv.z, sl * hv.w);
    int p = beg;
    for (; p + 4 <= end; p += 4) {
        int2 e0 = pairs[p], e1 = pairs[p + 1], e2 = pairs[p + 2], e3 = pairs[p + 3];
        float4 v0 = h4[(size_t)e0.x * C + c];
        float4 v1 = h4[(size_t)e1.x * C + c];
        float4 v2 = h4[(size_t)e2.x * C + c];
        float4 v3 = h4[(size_t)e3.x * C + c];
        float c0 = __int_as_float(e0.y), c1 = __int_as_float(e1.y);
        float c2 = __int_as_float(e2.y), c3 = __int_as_float(e3.y);
        acc.x += c0 * v0.x; acc.y += c0 * v0.y; acc.z += c0 * v0.z; acc.w += c0 * v0.w;
        acc.x += c1 * v1.x; acc.y += c1 * v1.y; acc.z += c1 * v1.z; acc.w += c1 * v1.w;
        acc.x += c2 * v2.x; acc.y += c2 * v2.y; acc.z += c2 * v2.z; acc.w += c2 * v2.w;
        acc.x += c3 * v3.x; acc.y += c3 * v3.y; acc.z += c3 * v3.z; acc.w += c3 * v3.w;
    }
    for (; p < end; ++p) {
        int2 pr = pairs[p];
        float coef = __int_as_float(pr.y);
        float4 v = h4[(size_t)pr.x * C + c];
        acc.x += coef * v.x; acc.y += coef * v.y;
        acc.z += coef * v.z; acc.w += coef * v.w;
    }
    float4 bb = *(const float4*)(b + c * 4);
    acc.x += bb.x; acc.y += bb.y; acc.z += bb.z; acc.w += bb.w;
    if (MODE == 0) {
        acc.x = fmaxf(acc.x, 0.f); acc.y = fmaxf(acc.y, 0.f);
        acc.z = fmaxf(acc.z, 0.f); acc.w = fmaxf(acc.w, 0.f);
        ((float4*)outp)[(size_t)n * C + c] = acc;
    } else {
        ((float4*)outp)[(size_t)n * C + c] = acc;
        ((float4*)outp)[(size_t)NN * C + (size_t)n * C + c] = acc;  // logstd = mu
    }
}

extern "C" void kernel_launch(void* const* d_in, const int* in_sizes, int n_in,
                              void* d_out, int out_size, void* d_ws, size_t ws_size,
                              hipStream_t stream) {
    const float* x  = (const float*)d_in[0];
    const int*   ei = (const int*)d_in[1];  // [2, NE] int32
    const float* W0 = (const float*)d_in[2];
    const float* b0 = (const float*)d_in[3];
    const float* W1 = (const float*)d_in[4];
    const float* b1 = (const float*)d_in[5];
    const float* W2 = (const float*)d_in[6];
    const float* b2 = (const float*)d_in[7];
    float* out = (float*)d_out;

    // ws: [cnt 51200][rowptr 51264][cursor 51200][bsum 64][boff 64]
    //     [dinv 51200f][pairs NE int2][bufH NN*96][bufA NN*96]
    int*   cnt    = (int*)d_ws;
    int*   rowptr = cnt + 51200;
    int*   cursor = rowptr + 51264;
    int*   bsum   = cursor + 51200;
    int*   boff   = bsum + 64;
    float* dinv   = (float*)(boff + 64);
    int2*  pairs  = (int2*)(dinv + 51200);
    float* bufH   = (float*)(pairs + NE);
    float* bufA   = bufH + (size_t)NN * 96;

    const int* src = ei;
    const int* dst = ei + NE;

    // CSR build (graph constant across layers; rebuilt identically every call)
    hipMemsetAsync(cnt, 0, NN * sizeof(int), stream);
    k_count<<<NE / 256, 256, 0, stream>>>(dst, cnt);
    k_scanA<<<NB, 1024, 0, stream>>>(cnt, rowptr, bsum, dinv);
    k_scanB<<<1, 64, 0, stream>>>(bsum, boff, rowptr);
    k_scanC<<<(NN + 255) / 256, 256, 0, stream>>>(rowptr, boff, cursor);
    k_fill<<<NE / 256, 256, 0, stream>>>(src, dst, dinv, cursor, pairs);

    constexpr int AG96 = (NN * 24 + 255) / 256;  // 4688
    constexpr int AG64 = NN * 16 / 256;          // 3125
    constexpr int GEMMG = (NN + 63) / 64;        // 782

    // layer 0: x -> bufA (relu)
    k_gemm<96, 96><<<GEMMG, 192, 0, stream>>>(x, W0, bufH);
    k_agg<96, 0><<<AG96, 256, 0, stream>>>(bufH, rowptr, pairs, dinv, b0, bufA);
    // layer 1: bufA -> bufA (relu)
    k_gemm<96, 96><<<GEMMG, 192, 0, stream>>>(bufA, W1, bufH);
    k_agg<96, 0><<<AG96, 256, 0, stream>>>(bufH, rowptr, pairs, dinv, b1, bufA);
    // layer 2: bufA -> out (mu, mirrored to logstd)
    k_gemm<96, 64><<<GEMMG, 128, 0, stream>>>(bufA, W2, bufH);
    k_agg<64, 1><<<AG64, 256, 0, stream>>>(bufH, rowptr, pairs, dinv, b2, out);
}

// Round 11
// 375.216 us; speedup vs baseline: 2.0293x; 1.0108x over previous
//
#include <hip/hip_runtime.h>

// VGAE encoder: 3x GCNConv (sym-norm + self loops), relu, relu, none.
// out = concat(mu, logstd=mu)
// Round 10: agg with 2 float4-chunks/thread + 4x edge unroll = 8 gathers in
// flight per lane (r9 confirmed latency-bound: 4x unroll dropped agg below
// 44us). scanB fused into scanC (one fewer launch in serial CSR chain).
constexpr int NN = 50000;   // nodes
constexpr int NE = 800000;  // edges
constexpr int NB = (NN + 1023) / 1024;  // 49 scan blocks

// ---- CSR build: count in-degree at dst -------------------------------------
__global__ void k_count(const int* __restrict__ dst, int* __restrict__ cnt) {
    int e = blockIdx.x * blockDim.x + threadIdx.x;
    if (e < NE) atomicAdd(&cnt[dst[e]], 1);
}

// ---- scan phase A: per-1024-block local exclusive prefix + block sum + dinv -
__global__ void __launch_bounds__(1024) k_scanA(const int* __restrict__ cnt,
                                                int* __restrict__ rowptr,
                                                int* __restrict__ bsum,
                                                float* __restrict__ dinv) {
    __shared__ int wsum[16];
    int tid = threadIdx.x;
    int lane = tid & 63, wid = tid >> 6;
    int i = blockIdx.x * 1024 + tid;
    int v = (i < NN) ? cnt[i] : 0;
    int x = v;
#pragma unroll
    for (int off = 1; off < 64; off <<= 1) {
        int t = __shfl_up(x, off);
        if (lane >= off) x += t;
    }
    if (lane == 63) wsum[wid] = x;
    __syncthreads();
    if (wid == 0) {
        int wt = (lane < 16) ? wsum[lane] : 0;
        int y = wt;
#pragma unroll
        for (int off = 1; off < 16; off <<= 1) {
            int t = __shfl_up(y, off);
            if (lane >= off) y += t;
        }
        if (lane < 16) wsum[lane] = y - wt;   // exclusive wave offsets
        if (lane == 15) bsum[blockIdx.x] = y; // block total
    }
    __syncthreads();
    if (i < NN) {
        rowptr[i] = wsum[wid] + (x - v);      // block-local exclusive prefix
        dinv[i] = rsqrtf((float)v + 1.0f);    // +1 self loop
    }
}

// ---- scan phase C (fused B): wave0 scans 49 block sums in LDS; apply -------
__global__ void k_scanC(int* __restrict__ rowptr, const int* __restrict__ bsum,
                        int* __restrict__ cursor) {
    __shared__ int sboff[64];
    int tid = threadIdx.x;
    if (tid < 64) {
        int v = (tid < NB) ? bsum[tid] : 0;
        int x = v;
#pragma unroll
        for (int off = 1; off < 64; off <<= 1) {
            int t = __shfl_up(x, off);
            if (tid >= off) x += t;
        }
        sboff[tid] = x - v;                   // exclusive block offsets
        if (blockIdx.x == 0 && tid == NB - 1) rowptr[NN] = x;  // total == NE
    }
    __syncthreads();
    int i = blockIdx.x * blockDim.x + tid;
    if (i < NN) {
        int r = rowptr[i] + sboff[i >> 10];
        rowptr[i] = r;
        cursor[i] = r;
    }
}

// ---- fill CSR with (src, coef) pairs ---------------------------------------
__global__ void k_fill(const int* __restrict__ src, const int* __restrict__ dst,
                       const float* __restrict__ dinv, int* __restrict__ cursor,
                       int2* __restrict__ pairs) {
    int e = blockIdx.x * blockDim.x + threadIdx.x;
    if (e >= NE) return;
    int s = src[e], d = dst[e];
    int pos = atomicAdd(&cursor[d], 1);
    float coef = dinv[s] * dinv[d];
    pairs[pos] = make_int2(s, __float_as_int(coef));
}

// ---- dense H = X @ W, LDS-staged, 4 rows x 2 float4 per thread -------------
template<int FIN, int FOUT>
__global__ void k_gemm(const float* __restrict__ X, const float* __restrict__ W,
                       float* __restrict__ H) {
    constexpr int ROWS = 64, RPT = 4, CPT = 2;
    constexpr int GC = FOUT / 4;       // float4 cols
    constexpr int CG = GC / CPT;       // col groups
    constexpr int RG = ROWS / RPT;     // row groups (16)
    constexpr int NT = RG * CG;        // threads
    __shared__ float sW[FIN * FOUT];
    __shared__ float sX[ROWS * FIN];
    int tid = threadIdx.x;
    int row0 = blockIdx.x * ROWS;
    for (int i = tid; i < FIN * GC; i += NT)
        ((float4*)sW)[i] = ((const float4*)W)[i];
    constexpr int XF4 = ROWS * FIN / 4;
    for (int i = tid; i < XF4; i += NT) {
        int r = i / (FIN / 4);
        int gr = row0 + r;
        ((float4*)sX)[i] = (gr < NN)
            ? ((const float4*)(X + (size_t)gr * FIN))[i % (FIN / 4)]
            : make_float4(0.f, 0.f, 0.f, 0.f);
    }
    __syncthreads();
    int rg = tid / CG, cg = tid % CG;
    int rbase = rg * RPT;
    float4 acc[RPT][CPT] = {};
    for (int k = 0; k < FIN; k += 4) {
        float4 xv[RPT];
#pragma unroll
        for (int i = 0; i < RPT; ++i)
            xv[i] = *(const float4*)&sX[(rbase + i) * FIN + k];
#pragma unroll
        for (int kk = 0; kk < 4; ++kk) {
#pragma unroll
            for (int j = 0; j < CPT; ++j) {
                float4 w4 = ((const float4*)sW)[(k + kk) * GC + cg * CPT + j];
#pragma unroll
                for (int i = 0; i < RPT; ++i) {
                    float xs = (&xv[i].x)[kk];
                    acc[i][j].x += xs * w4.x; acc[i][j].y += xs * w4.y;
                    acc[i][j].z += xs * w4.z; acc[i][j].w += xs * w4.w;
                }
            }
        }
    }
#pragma unroll
    for (int i = 0; i < RPT; ++i) {
        int gr = row0 + rbase + i;
        if (gr < NN)
#pragma unroll
            for (int j = 0; j < CPT; ++j)
                ((float4*)H)[(size_t)gr * GC + cg * CPT + j] = acc[i][j];
    }
}

// ---- gather aggregate + self-loop + bias (+relu | mirror) ------------------
// 2 consecutive float4 chunks per thread (T = C/2 threads per node), 4x edge
// unroll -> 8 gathers in flight per lane. Same per-element sum order as r4/r6.
// MODE 0: relu, write outp. MODE 1: write outp and mirror to outp+NN*F.
template<int F, int MODE>
__global__ void k_agg(const float* __restrict__ H, const int* __restrict__ rowptr,
                      const int2* __restrict__ pairs, const float* __restrict__ dinv,
                      const float* __restrict__ b, float* __restrict__ outp) {
    constexpr int C = F / 4;        // float4 chunks per row
    constexpr int T = C / 2;        // threads per node (12 @96, 8 @64)
    int tid = blockIdx.x * blockDim.x + threadIdx.x;
    int n = tid / T;
    int cc = (tid % T) * 2;         // first of two consecutive chunks
    if (n >= NN) return;
    int beg = rowptr[n], end = rowptr[n + 1];
    float di = dinv[n];
    const float4* h4 = (const float4*)H;
    size_t nb = (size_t)n * C + cc;
    float4 hv0 = h4[nb], hv1 = h4[nb + 1];
    float sl = di * di;
    float4 a0 = make_float4(sl * hv0.x, sl * hv0.y, sl * hv0.z, sl * hv0.w);
    float4 a1 = make_float4(sl * hv1.x, sl * hv1.y, sl * hv1.z, sl * hv1.w);
    int p = beg;
    for (; p + 4 <= end; p += 4) {
        int2 e0 = pairs[p], e1 = pairs[p + 1], e2 = pairs[p + 2], e3 = pairs[p + 3];
        size_t b0 = (size_t)e0.x * C + cc, b1 = (size_t)e1.x * C + cc;
        size_t b2 = (size_t)e2.x * C + cc, b3 = (size_t)e3.x * C + cc;
        float4 v0a = h4[b0], v0b = h4[b0 + 1];
        float4 v1a = h4[b1], v1b = h4[b1 + 1];
        float4 v2a = h4[b2], v2b = h4[b2 + 1];
        float4 v3a = h4[b3], v3b = h4[b3 + 1];
        float c0 = __int_as_float(e0.y), c1 = __int_as_float(e1.y);
        float c2 = __int_as_float(e2.y), c3 = __int_as_float(e3.y);
        a0.x += c0 * v0a.x; a0.y += c0 * v0a.y; a0.z += c0 * v0a.z; a0.w += c0 * v0a.w;
        a1.x += c0 * v0b.x; a1.y += c0 * v0b.y; a1.z += c0 * v0b.z; a1.w += c0 * v0b.w;
        a0.x += c1 * v1a.x; a0.y += c1 * v1a.y; a0.z += c1 * v1a.z; a0.w += c1 * v1a.w;
        a1.x += c1 * v1b.x; a1.y += c1 * v1b.y; a1.z += c1 * v1b.z; a1.w += c1 * v1b.w;
        a0.x += c2 * v2a.x; a0.y += c2 * v2a.y; a0.z += c2 * v2a.z; a0.w += c2 * v2a.w;
        a1.x += c2 * v2b.x; a1.y += c2 * v2b.y; a1.z += c2 * v2b.z; a1.w += c2 * v2b.w;
        a0.x += c3 * v3a.x; a0.y += c3 * v3a.y; a0.z += c3 * v3a.z; a0.w += c3 * v3a.w;
        a1.x += c3 * v3b.x; a1.y += c3 * v3b.y; a1.z += c3 * v3b.z; a1.w += c3 * v3b.w;
    }
    for (; p < end; ++p) {
        int2 pr = pairs[p];
        float coef = __int_as_float(pr.y);
        size_t bb = (size_t)pr.x * C + cc;
        float4 va = h4[bb], vb = h4[bb + 1];
        a0.x += coef * va.x; a0.y += coef * va.y; a0.z += coef * va.z; a0.w += coef * va.w;
        a1.x += coef * vb.x; a1.y += coef * vb.y; a1.z += coef * vb.z; a1.w += coef * vb.w;
    }
    float4 bb0 = *(const float4*)(b + cc * 4);
    float4 bb1 = *(const float4*)(b + cc * 4 + 4);
    a0.x += bb0.x; a0.y += bb0.y; a0.z += bb0.z; a0.w += bb0.w;
    a1.x += bb1.x; a1.y += bb1.y; a1.z += bb1.z; a1.w += bb1.w;
    if (MODE == 0) {
        a0.x = fmaxf(a0.x, 0.f); a0.y = fmaxf(a0.y, 0.f);
        a0.z = fmaxf(a0.z, 0.f); a0.w = fmaxf(a0.w, 0.f);
        a1.x = fmaxf(a1.x, 0.f); a1.y = fmaxf(a1.y, 0.f);
        a1.z = fmaxf(a1.z, 0.f); a1.w = fmaxf(a1.w, 0.f);
        ((float4*)outp)[nb] = a0;
        ((float4*)outp)[nb + 1] = a1;
    } else {
        ((float4*)outp)[nb] = a0;
        ((float4*)outp)[nb + 1] = a1;
        ((float4*)outp)[(size_t)NN * C + nb] = a0;      // logstd = mu
        ((float4*)outp)[(size_t)NN * C + nb + 1] = a1;
    }
}

extern "C" void kernel_launch(void* const* d_in, const int* in_sizes, int n_in,
                              void* d_out, int out_size, void* d_ws, size_t ws_size,
                              hipStream_t stream) {
    const float* x  = (const float*)d_in[0];
    const int*   ei = (const int*)d_in[1];  // [2, NE] int32
    const float* W0 = (const float*)d_in[2];
    const float* b0 = (const float*)d_in[3];
    const float* W1 = (const float*)d_in[4];
    const float* b1 = (const float*)d_in[5];
    const float* W2 = (const float*)d_in[6];
    const float* b2 = (const float*)d_in[7];
    float* out = (float*)d_out;

    // ws: [cnt 51200][rowptr 51264][cursor 51200][bsum 64]
    //     [dinv 51200f][pairs NE int2][bufH NN*96][bufA NN*96]
    int*   cnt    = (int*)d_ws;
    int*   rowptr = cnt + 51200;
    int*   cursor = rowptr + 51264;
    int*   bsum   = cursor + 51200;
    float* dinv   = (float*)(bsum + 64);
    int2*  pairs  = (int2*)(dinv + 51200);
    float* bufH   = (float*)(pairs + NE);
    float* bufA   = bufH + (size_t)NN * 96;

    const int* src = ei;
    const int* dst = ei + NE;

    // CSR build (graph constant across layers; rebuilt identically every call)
    hipMemsetAsync(cnt, 0, NN * sizeof(int), stream);
    k_count<<<NE / 256, 256, 0, stream>>>(dst, cnt);
    k_scanA<<<NB, 1024, 0, stream>>>(cnt, rowptr, bsum, dinv);
    k_scanC<<<(NN + 255) / 256, 256, 0, stream>>>(rowptr, bsum, cursor);
    k_fill<<<NE / 256, 256, 0, stream>>>(src, dst, dinv, cursor, pairs);

    // agg grids: 96-wide -> 12 thr/node, 192-thr blocks (16 nodes);
    //            64-wide -> 8 thr/node, 192-thr blocks (24 nodes)
    constexpr int AG96 = (NN * 12 + 191) / 192;  // 3125
    constexpr int AG64 = (NN * 8 + 191) / 192;   // 2084
    constexpr int GEMMG = (NN + 63) / 64;        // 782

    // layer 0: x -> bufA (relu)
    k_gemm<96, 96><<<GEMMG, 192, 0, stream>>>(x, W0, bufH);
    k_agg<96, 0><<<AG96, 192, 0, stream>>>(bufH, rowptr, pairs, dinv, b0, bufA);
    // layer 1: bufA -> bufA (relu)
    k_gemm<96, 96><<<GEMMG, 192, 0, stream>>>(bufA, W1, bufH);
    k_agg<96, 0><<<AG96, 192, 0, stream>>>(bufH, rowptr, pairs, dinv, b1, bufA);
    // layer 2: bufA -> out (mu, mirrored to logstd)
    k_gemm<96, 64><<<GEMMG, 128, 0, stream>>>(bufA, W2, bufH);
    k_agg<64, 1><<<AG64, 192, 0, stream>>>(bufH, rowptr, pairs, dinv, b2, out);
}

// Round 13
// 344.291 us; speedup vs baseline: 2.2116x; 1.0898x over previous
//
#include <hip/hip_runtime.h>
#include <hip/hip_fp16.h>

// VGAE encoder: 3x GCNConv (sym-norm + self loops), relu, relu, none.
// out = concat(mu, logstd=mu)
// Round 12: fp16 neighbor-gather path. r11 showed agg is random-gather
// BW/miss-bound (~3.5 TB/s, MLP 4->8 flat): halve bytes/row. GEMM writes
// fp32 H + packed fp16 H16; agg gathers fp16 (16B/lane/edge), fp32 math.
constexpr int NN = 50000;   // nodes
constexpr int NE = 800000;  // edges
constexpr int NB = (NN + 1023) / 1024;  // 49 scan blocks

// ---- CSR build: count in-degree at dst -------------------------------------
__global__ void k_count(const int* __restrict__ dst, int* __restrict__ cnt) {
    int e = blockIdx.x * blockDim.x + threadIdx.x;
    if (e < NE) atomicAdd(&cnt[dst[e]], 1);
}

// ---- scan phase A: per-1024-block local exclusive prefix + block sum + dinv -
__global__ void __launch_bounds__(1024) k_scanA(const int* __restrict__ cnt,
                                                int* __restrict__ rowptr,
                                                int* __restrict__ bsum,
                                                float* __restrict__ dinv) {
    __shared__ int wsum[16];
    int tid = threadIdx.x;
    int lane = tid & 63, wid = tid >> 6;
    int i = blockIdx.x * 1024 + tid;
    int v = (i < NN) ? cnt[i] : 0;
    int x = v;
#pragma unroll
    for (int off = 1; off < 64; off <<= 1) {
        int t = __shfl_up(x, off);
        if (lane >= off) x += t;
    }
    if (lane == 63) wsum[wid] = x;
    __syncthreads();
    if (wid == 0) {
        int wt = (lane < 16) ? wsum[lane] : 0;
        int y = wt;
#pragma unroll
        for (int off = 1; off < 16; off <<= 1) {
            int t = __shfl_up(y, off);
            if (lane >= off) y += t;
        }
        if (lane < 16) wsum[lane] = y - wt;   // exclusive wave offsets
        if (lane == 15) bsum[blockIdx.x] = y; // block total
    }
    __syncthreads();
    if (i < NN) {
        rowptr[i] = wsum[wid] + (x - v);      // block-local exclusive prefix
        dinv[i] = rsqrtf((float)v + 1.0f);    // +1 self loop
    }
}

// ---- scan phase C (fused B): wave0 scans 49 block sums in LDS; apply -------
__global__ void k_scanC(int* __restrict__ rowptr, const int* __restrict__ bsum,
                        int* __restrict__ cursor) {
    __shared__ int sboff[64];
    int tid = threadIdx.x;
    if (tid < 64) {
        int v = (tid < NB) ? bsum[tid] : 0;
        int x = v;
#pragma unroll
        for (int off = 1; off < 64; off <<= 1) {
            int t = __shfl_up(x, off);
            if (tid >= off) x += t;
        }
        sboff[tid] = x - v;                   // exclusive block offsets
        if (blockIdx.x == 0 && tid == NB - 1) rowptr[NN] = x;  // total == NE
    }
    __syncthreads();
    int i = blockIdx.x * blockDim.x + tid;
    if (i < NN) {
        int r = rowptr[i] + sboff[i >> 10];
        rowptr[i] = r;
        cursor[i] = r;
    }
}

// ---- fill CSR with (src, coef) pairs ---------------------------------------
__global__ void k_fill(const int* __restrict__ src, const int* __restrict__ dst,
                       const float* __restrict__ dinv, int* __restrict__ cursor,
                       int2* __restrict__ pairs) {
    int e = blockIdx.x * blockDim.x + threadIdx.x;
    if (e >= NE) return;
    int s = src[e], d = dst[e];
    int pos = atomicAdd(&cursor[d], 1);
    float coef = dinv[s] * dinv[d];
    pairs[pos] = make_int2(s, __float_as_int(coef));
}

// ---- dense H = X @ W -> fp32 H and packed fp16 H16 -------------------------
template<int FIN, int FOUT>
__global__ void k_gemm(const float* __restrict__ X, const float* __restrict__ W,
                       float* __restrict__ H, __half* __restrict__ H16) {
    constexpr int ROWS = 64, RPT = 4, CPT = 2;
    constexpr int GC = FOUT / 4;       // float4 cols
    constexpr int CG = GC / CPT;       // col groups
    constexpr int RG = ROWS / RPT;     // row groups (16)
    constexpr int NT = RG * CG;        // threads
    __shared__ float sW[FIN * FOUT];
    __shared__ float sX[ROWS * FIN];
    int tid = threadIdx.x;
    int row0 = blockIdx.x * ROWS;
    for (int i = tid; i < FIN * GC; i += NT)
        ((float4*)sW)[i] = ((const float4*)W)[i];
    constexpr int XF4 = ROWS * FIN / 4;
    for (int i = tid; i < XF4; i += NT) {
        int r = i / (FIN / 4);
        int gr = row0 + r;
        ((float4*)sX)[i] = (gr < NN)
            ? ((const float4*)(X + (size_t)gr * FIN))[i % (FIN / 4)]
            : make_float4(0.f, 0.f, 0.f, 0.f);
    }
    __syncthreads();
    int rg = tid / CG, cg = tid % CG;
    int rbase = rg * RPT;
    float4 acc[RPT][CPT] = {};
    for (int k = 0; k < FIN; k += 4) {
        float4 xv[RPT];
#pragma unroll
        for (int i = 0; i < RPT; ++i)
            xv[i] = *(const float4*)&sX[(rbase + i) * FIN + k];
#pragma unroll
        for (int kk = 0; kk < 4; ++kk) {
#pragma unroll
            for (int j = 0; j < CPT; ++j) {
                float4 w4 = ((const float4*)sW)[(k + kk) * GC + cg * CPT + j];
#pragma unroll
                for (int i = 0; i < RPT; ++i) {
                    float xs = (&xv[i].x)[kk];
                    acc[i][j].x += xs * w4.x; acc[i][j].y += xs * w4.y;
                    acc[i][j].z += xs * w4.z; acc[i][j].w += xs * w4.w;
                }
            }
        }
    }
#pragma unroll
    for (int i = 0; i < RPT; ++i) {
        int gr = row0 + rbase + i;
        if (gr < NN) {
#pragma unroll
            for (int j = 0; j < CPT; ++j)
                ((float4*)H)[(size_t)gr * GC + cg * CPT + j] = acc[i][j];
            // packed fp16 copy: 8 cols -> 4 half2 -> one 16B store
            __half2 hp[4];
            hp[0] = __float22half2_rn(make_float2(acc[i][0].x, acc[i][0].y));
            hp[1] = __float22half2_rn(make_float2(acc[i][0].z, acc[i][0].w));
            hp[2] = __float22half2_rn(make_float2(acc[i][1].x, acc[i][1].y));
            hp[3] = __float22half2_rn(make_float2(acc[i][1].z, acc[i][1].w));
            ((float4*)H16)[(size_t)gr * (FOUT / 8) + cg] = *(float4*)hp;
        }
    }
}

// ---- gather aggregate + self-loop + bias (+relu | mirror), fp16 gathers ----
// T = F/8 threads per node; each owns 8 features. Neighbor rows read from
// fp16 H16 (16B/lane/edge, 4 edges in flight); self-loop from fp32 H.
// MODE 0: relu, write outp. MODE 1: write outp and mirror to outp+NN*F.
template<int F, int MODE>
__global__ void k_agg(const float* __restrict__ H, const __half* __restrict__ H16,
                      const int* __restrict__ rowptr, const int2* __restrict__ pairs,
                      const float* __restrict__ dinv, const float* __restrict__ b,
                      float* __restrict__ outp) {
    constexpr int C = F / 4;        // float4 chunks per fp32 row
    constexpr int T = F / 8;        // threads per node (12 @96, 8 @64)
    int tid = blockIdx.x * blockDim.x + threadIdx.x;
    int n = tid / T;
    int q = tid % T;                // 8-feature group
    if (n >= NN) return;
    int beg = rowptr[n], end = rowptr[n + 1];
    float di = dinv[n];
    const float4* h4 = (const float4*)H;
    const float4* g16 = (const float4*)H16;  // T units of 16B per row
    size_t nb = (size_t)n * C + q * 2;
    float4 hv0 = h4[nb], hv1 = h4[nb + 1];
    float sl = di * di;
    float4 a0 = make_float4(sl * hv0.x, sl * hv0.y, sl * hv0.z, sl * hv0.w);
    float4 a1 = make_float4(sl * hv1.x, sl * hv1.y, sl * hv1.z, sl * hv1.w);
    int p = beg;
#define ACC8(raw, cf)                                                          \
    {                                                                          \
        const __half2* hp_ = (const __half2*)&(raw);                           \
        float2 f0_ = __half22float2(hp_[0]); float2 f1_ = __half22float2(hp_[1]); \
        float2 f2_ = __half22float2(hp_[2]); float2 f3_ = __half22float2(hp_[3]); \
        a0.x += (cf) * f0_.x; a0.y += (cf) * f0_.y;                            \
        a0.z += (cf) * f1_.x; a0.w += (cf) * f1_.y;                            \
        a1.x += (cf) * f2_.x; a1.y += (cf) * f2_.y;                            \
        a1.z += (cf) * f3_.x; a1.w += (cf) * f3_.y;                            \
    }
    for (; p + 4 <= end; p += 4) {
        int2 e0 = pairs[p], e1 = pairs[p + 1], e2 = pairs[p + 2], e3 = pairs[p + 3];
        float4 r0 = g16[(size_t)e0.x * T + q];
        float4 r1 = g16[(size_t)e1.x * T + q];
        float4 r2 = g16[(size_t)e2.x * T + q];
        float4 r3 = g16[(size_t)e3.x * T + q];
        ACC8(r0, __int_as_float(e0.y));
        ACC8(r1, __int_as_float(e1.y));
        ACC8(r2, __int_as_float(e2.y));
        ACC8(r3, __int_as_float(e3.y));
    }
    for (; p < end; ++p) {
        int2 pr = pairs[p];
        float4 r = g16[(size_t)pr.x * T + q];
        ACC8(r, __int_as_float(pr.y));
    }
#undef ACC8
    float4 bb0 = *(const float4*)(b + q * 8);
    float4 bb1 = *(const float4*)(b + q * 8 + 4);
    a0.x += bb0.x; a0.y += bb0.y; a0.z += bb0.z; a0.w += bb0.w;
    a1.x += bb1.x; a1.y += bb1.y; a1.z += bb1.z; a1.w += bb1.w;
    if (MODE == 0) {
        a0.x = fmaxf(a0.x, 0.f); a0.y = fmaxf(a0.y, 0.f);
        a0.z = fmaxf(a0.z, 0.f); a0.w = fmaxf(a0.w, 0.f);
        a1.x = fmaxf(a1.x, 0.f); a1.y = fmaxf(a1.y, 0.f);
        a1.z = fmaxf(a1.z, 0.f); a1.w = fmaxf(a1.w, 0.f);
        ((float4*)outp)[nb] = a0;
        ((float4*)outp)[nb + 1] = a1;
    } else {
        ((float4*)outp)[nb] = a0;
        ((float4*)outp)[nb + 1] = a1;
        ((float4*)outp)[(size_t)NN * C + nb] = a0;      // logstd = mu
        ((float4*)outp)[(size_t)NN * C + nb + 1] = a1;
    }
}

extern "C" void kernel_launch(void* const* d_in, const int* in_sizes, int n_in,
                              void* d_out, int out_size, void* d_ws, size_t ws_size,
                              hipStream_t stream) {
    const float* x  = (const float*)d_in[0];
    const int*   ei = (const int*)d_in[1];  // [2, NE] int32
    const float* W0 = (const float*)d_in[2];
    const float* b0 = (const float*)d_in[3];
    const float* W1 = (const float*)d_in[4];
    const float* b1 = (const float*)d_in[5];
    const float* W2 = (const float*)d_in[6];
    const float* b2 = (const float*)d_in[7];
    float* out = (float*)d_out;

    // ws: [cnt 51200][rowptr 51264][cursor 51200][bsum 64]
    //     [dinv 51200f][pairs NE int2][bufH NN*96 f][bufA NN*96 f][bufH16 NN*96 half]
    int*    cnt    = (int*)d_ws;
    int*    rowptr = cnt + 51200;
    int*    cursor = rowptr + 51264;
    int*    bsum   = cursor + 51200;
    float*  dinv   = (float*)(bsum + 64);
    int2*   pairs  = (int2*)(dinv + 51200);
    float*  bufH   = (float*)(pairs + NE);
    float*  bufA   = bufH + (size_t)NN * 96;
    __half* bufH16 = (__half*)(bufA + (size_t)NN * 96);

    const int* src = ei;
    const int* dst = ei + NE;

    // CSR build (graph constant across layers; rebuilt identically every call)
    hipMemsetAsync(cnt, 0, NN * sizeof(int), stream);
    k_count<<<NE / 256, 256, 0, stream>>>(dst, cnt);
    k_scanA<<<NB, 1024, 0, stream>>>(cnt, rowptr, bsum, dinv);
    k_scanC<<<(NN + 255) / 256, 256, 0, stream>>>(rowptr, bsum, cursor);
    k_fill<<<NE / 256, 256, 0, stream>>>(src, dst, dinv, cursor, pairs);

    // agg grids: 96-wide -> 12 thr/node; 64-wide -> 8 thr/node (192-thr blocks)
    constexpr int AG96 = (NN * 12 + 191) / 192;  // 3125
    constexpr int AG64 = (NN * 8 + 191) / 192;   // 2084
    constexpr int GEMMG = (NN + 63) / 64;        // 782

    // layer 0: x -> bufA (relu)
    k_gemm<96, 96><<<GEMMG, 192, 0, stream>>>(x, W0, bufH, bufH16);
    k_agg<96, 0><<<AG96, 192, 0, stream>>>(bufH, bufH16, rowptr, pairs, dinv, b0, bufA);
    // layer 1: bufA -> bufA (relu)
    k_gemm<96, 96><<<GEMMG, 192, 0, stream>>>(bufA, W1, bufH, bufH16);
    k_agg<96, 0><<<AG96, 192, 0, stream>>>(bufH, bufH16, rowptr, pairs, dinv, b1, bufA);
    // layer 2: bufA -> out (mu, mirrored to logstd)
    k_gemm<96, 64><<<GEMMG, 128, 0, stream>>>(bufA, W2, bufH, bufH16);
    k_agg<64, 1><<<AG64, 192, 0, stream>>>(bufH, bufH16, rowptr, pairs, dinv, b2, out);
}

// Round 14
// 329.581 us; speedup vs baseline: 2.3103x; 1.0446x over previous
//
#include <hip/hip_runtime.h>
#include <hip/hip_fp16.h>

// VGAE encoder: 3x GCNConv (sym-norm + self loops), relu, relu, none.
// out = concat(mu, logstd=mu)
// Round 14: drop fp32 H entirely. GEMM writes only packed fp16 H16 (9.6MB);
// agg reads self-loop row AND neighbors from H16 (fp32 accumulate). Saves
// ~38MB traffic/layer; gather working set 9.6MB -> better per-XCD L2 hits.
constexpr int NN = 50000;   // nodes
constexpr int NE = 800000;  // edges
constexpr int NB = (NN + 1023) / 1024;  // 49 scan blocks

// ---- CSR build: count in-degree at dst -------------------------------------
__global__ void k_count(const int* __restrict__ dst, int* __restrict__ cnt) {
    int e = blockIdx.x * blockDim.x + threadIdx.x;
    if (e < NE) atomicAdd(&cnt[dst[e]], 1);
}

// ---- scan phase A: per-1024-block local exclusive prefix + block sum + dinv -
__global__ void __launch_bounds__(1024) k_scanA(const int* __restrict__ cnt,
                                                int* __restrict__ rowptr,
                                                int* __restrict__ bsum,
                                                float* __restrict__ dinv) {
    __shared__ int wsum[16];
    int tid = threadIdx.x;
    int lane = tid & 63, wid = tid >> 6;
    int i = blockIdx.x * 1024 + tid;
    int v = (i < NN) ? cnt[i] : 0;
    int x = v;
#pragma unroll
    for (int off = 1; off < 64; off <<= 1) {
        int t = __shfl_up(x, off);
        if (lane >= off) x += t;
    }
    if (lane == 63) wsum[wid] = x;
    __syncthreads();
    if (wid == 0) {
        int wt = (lane < 16) ? wsum[lane] : 0;
        int y = wt;
#pragma unroll
        for (int off = 1; off < 16; off <<= 1) {
            int t = __shfl_up(y, off);
            if (lane >= off) y += t;
        }
        if (lane < 16) wsum[lane] = y - wt;   // exclusive wave offsets
        if (lane == 15) bsum[blockIdx.x] = y; // block total
    }
    __syncthreads();
    if (i < NN) {
        rowptr[i] = wsum[wid] + (x - v);      // block-local exclusive prefix
        dinv[i] = rsqrtf((float)v + 1.0f);    // +1 self loop
    }
}

// ---- scan phase C (fused B): wave0 scans 49 block sums in LDS; apply -------
__global__ void k_scanC(int* __restrict__ rowptr, const int* __restrict__ bsum,
                        int* __restrict__ cursor) {
    __shared__ int sboff[64];
    int tid = threadIdx.x;
    if (tid < 64) {
        int v = (tid < NB) ? bsum[tid] : 0;
        int x = v;
#pragma unroll
        for (int off = 1; off < 64; off <<= 1) {
            int t = __shfl_up(x, off);
            if (tid >= off) x += t;
        }
        sboff[tid] = x - v;                   // exclusive block offsets
        if (blockIdx.x == 0 && tid == NB - 1) rowptr[NN] = x;  // total == NE
    }
    __syncthreads();
    int i = blockIdx.x * blockDim.x + tid;
    if (i < NN) {
        int r = rowptr[i] + sboff[i >> 10];
        rowptr[i] = r;
        cursor[i] = r;
    }
}

// ---- fill CSR with (src, coef) pairs ---------------------------------------
__global__ void k_fill(const int* __restrict__ src, const int* __restrict__ dst,
                       const float* __restrict__ dinv, int* __restrict__ cursor,
                       int2* __restrict__ pairs) {
    int e = blockIdx.x * blockDim.x + threadIdx.x;
    if (e >= NE) return;
    int s = src[e], d = dst[e];
    int pos = atomicAdd(&cursor[d], 1);
    float coef = dinv[s] * dinv[d];
    pairs[pos] = make_int2(s, __float_as_int(coef));
}

// ---- dense H16 = fp16(X @ W), LDS-staged, 4 rows x 8 cols per thread -------
template<int FIN, int FOUT>
__global__ void k_gemm(const float* __restrict__ X, const float* __restrict__ W,
                       __half* __restrict__ H16) {
    constexpr int ROWS = 64, RPT = 4, CPT = 2;
    constexpr int GC = FOUT / 4;       // float4 cols
    constexpr int CG = GC / CPT;       // col groups (8-col units)
    constexpr int RG = ROWS / RPT;     // row groups (16)
    constexpr int NT = RG * CG;        // threads
    __shared__ float sW[FIN * FOUT];
    __shared__ float sX[ROWS * FIN];
    int tid = threadIdx.x;
    int row0 = blockIdx.x * ROWS;
    for (int i = tid; i < FIN * GC; i += NT)
        ((float4*)sW)[i] = ((const float4*)W)[i];
    constexpr int XF4 = ROWS * FIN / 4;
    for (int i = tid; i < XF4; i += NT) {
        int r = i / (FIN / 4);
        int gr = row0 + r;
        ((float4*)sX)[i] = (gr < NN)
            ? ((const float4*)(X + (size_t)gr * FIN))[i % (FIN / 4)]
            : make_float4(0.f, 0.f, 0.f, 0.f);
    }
    __syncthreads();
    int rg = tid / CG, cg = tid % CG;
    int rbase = rg * RPT;
    float4 acc[RPT][CPT] = {};
    for (int k = 0; k < FIN; k += 4) {
        float4 xv[RPT];
#pragma unroll
        for (int i = 0; i < RPT; ++i)
            xv[i] = *(const float4*)&sX[(rbase + i) * FIN + k];
#pragma unroll
        for (int kk = 0; kk < 4; ++kk) {
#pragma unroll
            for (int j = 0; j < CPT; ++j) {
                float4 w4 = ((const float4*)sW)[(k + kk) * GC + cg * CPT + j];
#pragma unroll
                for (int i = 0; i < RPT; ++i) {
                    float xs = (&xv[i].x)[kk];
                    acc[i][j].x += xs * w4.x; acc[i][j].y += xs * w4.y;
                    acc[i][j].z += xs * w4.z; acc[i][j].w += xs * w4.w;
                }
            }
        }
    }
#pragma unroll
    for (int i = 0; i < RPT; ++i) {
        int gr = row0 + rbase + i;
        if (gr < NN) {
            // packed fp16: 8 cols -> 4 half2 -> one 16B store
            __half2 hp[4];
            hp[0] = __float22half2_rn(make_float2(acc[i][0].x, acc[i][0].y));
            hp[1] = __float22half2_rn(make_float2(acc[i][0].z, acc[i][0].w));
            hp[2] = __float22half2_rn(make_float2(acc[i][1].x, acc[i][1].y));
            hp[3] = __float22half2_rn(make_float2(acc[i][1].z, acc[i][1].w));
            ((float4*)H16)[(size_t)gr * (FOUT / 8) + cg] = *(float4*)hp;
        }
    }
}

// ---- gather aggregate + self-loop + bias (+relu | mirror), all-fp16 h ------
// T = F/8 threads per node; each owns 8 features (one 16B fp16 unit).
// Neighbors AND self row read from H16; accumulate fp32; output fp32.
// MODE 0: relu, write outp. MODE 1: write outp and mirror to outp+NN*F.
template<int F, int MODE>
__global__ void k_agg(const __half* __restrict__ H16,
                      const int* __restrict__ rowptr, const int2* __restrict__ pairs,
                      const float* __restrict__ dinv, const float* __restrict__ b,
                      float* __restrict__ outp) {
    constexpr int C = F / 4;        // float4 chunks per fp32 out row
    constexpr int T = F / 8;        // threads per node (12 @96, 8 @64)
    int tid = blockIdx.x * blockDim.x + threadIdx.x;
    int n = tid / T;
    int q = tid % T;                // 8-feature group
    if (n >= NN) return;
    int beg = rowptr[n], end = rowptr[n + 1];
    float di = dinv[n];
    const float4* g16 = (const float4*)H16;  // T units of 16B per row
    float4 a0 = make_float4(0.f, 0.f, 0.f, 0.f);
    float4 a1 = make_float4(0.f, 0.f, 0.f, 0.f);
#define ACC8(raw, cf)                                                          \
    {                                                                          \
        const __half2* hp_ = (const __half2*)&(raw);                           \
        float2 f0_ = __half22float2(hp_[0]); float2 f1_ = __half22float2(hp_[1]); \
        float2 f2_ = __half22float2(hp_[2]); float2 f3_ = __half22float2(hp_[3]); \
        a0.x += (cf) * f0_.x; a0.y += (cf) * f0_.y;                            \
        a0.z += (cf) * f1_.x; a0.w += (cf) * f1_.y;                            \
        a1.x += (cf) * f2_.x; a1.y += (cf) * f2_.y;                            \
        a1.z += (cf) * f3_.x; a1.w += (cf) * f3_.y;                            \
    }
    // self-loop term
    {
        float4 rs = g16[(size_t)n * T + q];
        ACC8(rs, di * di);
    }
    int p = beg;
    for (; p + 4 <= end; p += 4) {
        int2 e0 = pairs[p], e1 = pairs[p + 1], e2 = pairs[p + 2], e3 = pairs[p + 3];
        float4 r0 = g16[(size_t)e0.x * T + q];
        float4 r1 = g16[(size_t)e1.x * T + q];
        float4 r2 = g16[(size_t)e2.x * T + q];
        float4 r3 = g16[(size_t)e3.x * T + q];
        ACC8(r0, __int_as_float(e0.y));
        ACC8(r1, __int_as_float(e1.y));
        ACC8(r2, __int_as_float(e2.y));
        ACC8(r3, __int_as_float(e3.y));
    }
    for (; p < end; ++p) {
        int2 pr = pairs[p];
        float4 r = g16[(size_t)pr.x * T + q];
        ACC8(r, __int_as_float(pr.y));
    }
#undef ACC8
    float4 bb0 = *(const float4*)(b + q * 8);
    float4 bb1 = *(const float4*)(b + q * 8 + 4);
    a0.x += bb0.x; a0.y += bb0.y; a0.z += bb0.z; a0.w += bb0.w;
    a1.x += bb1.x; a1.y += bb1.y; a1.z += bb1.z; a1.w += bb1.w;
    size_t nb = (size_t)n * C + q * 2;
    if (MODE == 0) {
        a0.x = fmaxf(a0.x, 0.f); a0.y = fmaxf(a0.y, 0.f);
        a0.z = fmaxf(a0.z, 0.f); a0.w = fmaxf(a0.w, 0.f);
        a1.x = fmaxf(a1.x, 0.f); a1.y = fmaxf(a1.y, 0.f);
        a1.z = fmaxf(a1.z, 0.f); a1.w = fmaxf(a1.w, 0.f);
        ((float4*)outp)[nb] = a0;
        ((float4*)outp)[nb + 1] = a1;
    } else {
        ((float4*)outp)[nb] = a0;
        ((float4*)outp)[nb + 1] = a1;
        ((float4*)outp)[(size_t)NN * C + nb] = a0;      // logstd = mu
        ((float4*)outp)[(size_t)NN * C + nb + 1] = a1;
    }
}

extern "C" void kernel_launch(void* const* d_in, const int* in_sizes, int n_in,
                              void* d_out, int out_size, void* d_ws, size_t ws_size,
                              hipStream_t stream) {
    const float* x  = (const float*)d_in[0];
    const int*   ei = (const int*)d_in[1];  // [2, NE] int32
    const float* W0 = (const float*)d_in[2];
    const float* b0 = (const float*)d_in[3];
    const float* W1 = (const float*)d_in[4];
    const float* b1 = (const float*)d_in[5];
    const float* W2 = (const float*)d_in[6];
    const float* b2 = (const float*)d_in[7];
    float* out = (float*)d_out;

    // ws: [cnt 51200][rowptr 51264][cursor 51200][bsum 64]
    //     [dinv 51200f][pairs NE int2][bufA NN*96 f][bufH16 NN*96 half]
    int*    cnt    = (int*)d_ws;
    int*    rowptr = cnt + 51200;
    int*    cursor = rowptr + 51264;
    int*    bsum   = cursor + 51200;
    float*  dinv   = (float*)(bsum + 64);
    int2*   pairs  = (int2*)(dinv + 51200);
    float*  bufA   = (float*)(pairs + NE);
    __half* bufH16 = (__half*)(bufA + (size_t)NN * 96);

    const int* src = ei;
    const int* dst = ei + NE;

    // CSR build (graph constant across layers; rebuilt identically every call)
    hipMemsetAsync(cnt, 0, NN * sizeof(int), stream);
    k_count<<<NE / 256, 256, 0, stream>>>(dst, cnt);
    k_scanA<<<NB, 1024, 0, stream>>>(cnt, rowptr, bsum, dinv);
    k_scanC<<<(NN + 255) / 256, 256, 0, stream>>>(rowptr, bsum, cursor);
    k_fill<<<NE / 256, 256, 0, stream>>>(src, dst, dinv, cursor, pairs);

    // agg grids: 96-wide -> 12 thr/node; 64-wide -> 8 thr/node (192-thr blocks)
    constexpr int AG96 = (NN * 12 + 191) / 192;  // 3125
    constexpr int AG64 = (NN * 8 + 191) / 192;   // 2084
    constexpr int GEMMG = (NN + 63) / 64;        // 782

    // layer 0: x -> bufA (relu)
    k_gemm<96, 96><<<GEMMG, 192, 0, stream>>>(x, W0, bufH16);
    k_agg<96, 0><<<AG96, 192, 0, stream>>>(bufH16, rowptr, pairs, dinv, b0, bufA);
    // layer 1: bufA -> bufA (relu)
    k_gemm<96, 96><<<GEMMG, 192, 0, stream>>>(bufA, W1, bufH16);
    k_agg<96, 0><<<AG96, 192, 0, stream>>>(bufH16, rowptr, pairs, dinv, b1, bufA);
    // layer 2: bufA -> out (mu, mirrored to logstd)
    k_gemm<96, 64><<<GEMMG, 128, 0, stream>>>(bufA, W2, bufH16);
    k_agg<64, 1><<<AG64, 192, 0, stream>>>(bufH16, rowptr, pairs, dinv, b2, out);
}

// Round 15
// 323.267 us; speedup vs baseline: 2.3554x; 1.0195x over previous
//
#include <hip/hip_runtime.h>
#include <hip/hip_fp16.h>

// VGAE encoder: 3x GCNConv (sym-norm + self loops), relu, relu, none.
// out = concat(mu, logstd=mu)
// Round 15: GEMM LDS bank-conflict fix (k-major sXT transpose: 6-way -> 0;
// j-interleaved sW: 3-way -> free). rowptr-shift trick removes cursor array.
// h kept packed fp16 (r13/r14); agg math unchanged (absmax bit-identical).
constexpr int NN = 50000;   // nodes
constexpr int NE = 800000;  // edges
constexpr int NB = (NN + 1023) / 1024;  // 49 scan blocks

// ---- CSR build: count in-degree at dst -------------------------------------
__global__ void k_count(const int* __restrict__ dst, int* __restrict__ cnt) {
    int e = blockIdx.x * blockDim.x + threadIdx.x;
    if (e < NE) atomicAdd(&cnt[dst[e]], 1);
}

// ---- scan phase A: per-1024-block local exclusive prefix + block sum + dinv -
__global__ void __launch_bounds__(1024) k_scanA(const int* __restrict__ cnt,
                                                int* __restrict__ rowptr,
                                                int* __restrict__ bsum,
                                                float* __restrict__ dinv) {
    __shared__ int wsum[16];
    int tid = threadIdx.x;
    int lane = tid & 63, wid = tid >> 6;
    int i = blockIdx.x * 1024 + tid;
    int v = (i < NN) ? cnt[i] : 0;
    int x = v;
#pragma unroll
    for (int off = 1; off < 64; off <<= 1) {
        int t = __shfl_up(x, off);
        if (lane >= off) x += t;
    }
    if (lane == 63) wsum[wid] = x;
    __syncthreads();
    if (wid == 0) {
        int wt = (lane < 16) ? wsum[lane] : 0;
        int y = wt;
#pragma unroll
        for (int off = 1; off < 16; off <<= 1) {
            int t = __shfl_up(y, off);
            if (lane >= off) y += t;
        }
        if (lane < 16) wsum[lane] = y - wt;   // exclusive wave offsets
        if (lane == 15) bsum[blockIdx.x] = y; // block total
    }
    __syncthreads();
    if (i < NN) {
        rowptr[i] = wsum[wid] + (x - v);      // block-local exclusive prefix
        dinv[i] = rsqrtf((float)v + 1.0f);    // +1 self loop
    }
}

// ---- scan phase C (fused B): wave0 scans 49 block sums in LDS; apply -------
__global__ void k_scanC(int* __restrict__ rowptr, const int* __restrict__ bsum) {
    __shared__ int sboff[64];
    int tid = threadIdx.x;
    if (tid < 64) {
        int v = (tid < NB) ? bsum[tid] : 0;
        int x = v;
#pragma unroll
        for (int off = 1; off < 64; off <<= 1) {
            int t = __shfl_up(x, off);
            if (tid >= off) x += t;
        }
        sboff[tid] = x - v;                   // exclusive block offsets
    }
    __syncthreads();
    int i = blockIdx.x * blockDim.x + tid;
    if (i < NN) rowptr[i] += sboff[i >> 10];
}

// ---- fill CSR with (src, coef) pairs; atomicAdd shifts rowptr by one -------
// After this kernel rowptr[n] == exclusive_prefix[n+1]; agg reads
// [rowptr[n-1], rowptr[n]) with rowptr[-1] == 0.
__global__ void k_fill(const int* __restrict__ src, const int* __restrict__ dst,
                       const float* __restrict__ dinv, int* __restrict__ rowptr,
                       int2* __restrict__ pairs) {
    int e = blockIdx.x * blockDim.x + threadIdx.x;
    if (e >= NE) return;
    int s = src[e], d = dst[e];
    int pos = atomicAdd(&rowptr[d], 1);
    float coef = dinv[s] * dinv[d];
    pairs[pos] = make_int2(s, __float_as_int(coef));
}

// ---- dense H16 = fp16(X @ W), k-major LDS (conflict-free reads) ------------
// sXT[k][64]: thread's 4 rows at one k are one aligned float4; rg lanes hit
// banks 4*rg (distinct), cg lanes broadcast. sW read j-interleaved (cg+j*CG):
// cg stride 1 float4 -> <=2-way. Thread covers cols 4*(cg+j*CG)..+3, j=0,1.
template<int FIN, int FOUT>
__global__ void k_gemm(const float* __restrict__ X, const float* __restrict__ W,
                       __half* __restrict__ H16) {
    constexpr int ROWS = 64, RPT = 4, CPT = 2;
    constexpr int GC = FOUT / 4;       // float4 cols (24 / 16)
    constexpr int CG = GC / CPT;       // col groups (12 / 8)
    constexpr int RG = ROWS / RPT;     // row groups (16)
    constexpr int NT = RG * CG;        // threads (192 / 128)
    __shared__ float sW[FIN * FOUT];   // k-major: float4 idx k*GC + c
    __shared__ float sXT[FIN * ROWS];  // transposed: sXT[k*64 + r]
    int tid = threadIdx.x;
    int row0 = blockIdx.x * ROWS;
    for (int i = tid; i < FIN * GC; i += NT)
        ((float4*)sW)[i] = ((const float4*)W)[i];
    constexpr int XF4 = ROWS * FIN / 4;  // 1536
    for (int i = tid; i < XF4; i += NT) {
        int r = i & 63;
        int k4 = i >> 6;
        int gr = row0 + r;
        float4 v = (gr < NN) ? ((const float4*)(X + (size_t)gr * FIN))[k4]
                             : make_float4(0.f, 0.f, 0.f, 0.f);
        sXT[(k4 * 4 + 0) * ROWS + r] = v.x;
        sXT[(k4 * 4 + 1) * ROWS + r] = v.y;
        sXT[(k4 * 4 + 2) * ROWS + r] = v.z;
        sXT[(k4 * 4 + 3) * ROWS + r] = v.w;
    }
    __syncthreads();
    int rg = tid / CG, cg = tid % CG;
    int rbase = rg * RPT;
    float4 acc[RPT][CPT] = {};
    for (int k = 0; k < FIN; ++k) {
        float4 xk = *(const float4*)&sXT[k * ROWS + rbase];  // 4 rows @ k
#pragma unroll
        for (int j = 0; j < CPT; ++j) {
            float4 w4 = ((const float4*)sW)[k * GC + cg + j * CG];
#pragma unroll
            for (int i = 0; i < RPT; ++i) {
                float xs = (&xk.x)[i];
                acc[i][j].x += xs * w4.x; acc[i][j].y += xs * w4.y;
                acc[i][j].z += xs * w4.z; acc[i][j].w += xs * w4.w;
            }
        }
    }
#pragma unroll
    for (int i = 0; i < RPT; ++i) {
        int gr = row0 + rbase + i;
        if (gr < NN) {
#pragma unroll
            for (int j = 0; j < CPT; ++j) {
                float2 pk;
                ((__half2*)&pk)[0] = __float22half2_rn(make_float2(acc[i][j].x, acc[i][j].y));
                ((__half2*)&pk)[1] = __float22half2_rn(make_float2(acc[i][j].z, acc[i][j].w));
                ((float2*)(H16 + (size_t)gr * FOUT))[cg + j * CG] = pk;  // 8B store
            }
        }
    }
}

// ---- gather aggregate + self-loop + bias (+relu | mirror), all-fp16 h ------
// T = F/8 threads per node; each owns 8 features (one 16B fp16 unit).
// MODE 0: relu, write outp. MODE 1: write outp and mirror to outp+NN*F.
template<int F, int MODE>
__global__ void k_agg(const __half* __restrict__ H16,
                      const int* __restrict__ rowptr, const int2* __restrict__ pairs,
                      const float* __restrict__ dinv, const float* __restrict__ b,
                      float* __restrict__ outp) {
    constexpr int C = F / 4;        // float4 chunks per fp32 out row
    constexpr int T = F / 8;        // threads per node (12 @96, 8 @64)
    int tid = blockIdx.x * blockDim.x + threadIdx.x;
    int n = tid / T;
    int q = tid % T;                // 8-feature group
    if (n >= NN) return;
    int beg = (n > 0) ? rowptr[n - 1] : 0;  // rowptr shifted by k_fill
    int end = rowptr[n];
    float di = dinv[n];
    const float4* g16 = (const float4*)H16;  // T units of 16B per row
    float4 a0 = make_float4(0.f, 0.f, 0.f, 0.f);
    float4 a1 = make_float4(0.f, 0.f, 0.f, 0.f);
#define ACC8(raw, cf)                                                          \
    {                                                                          \
        const __half2* hp_ = (const __half2*)&(raw);                           \
        float2 f0_ = __half22float2(hp_[0]); float2 f1_ = __half22float2(hp_[1]); \
        float2 f2_ = __half22float2(hp_[2]); float2 f3_ = __half22float2(hp_[3]); \
        a0.x += (cf) * f0_.x; a0.y += (cf) * f0_.y;                            \
        a0.z += (cf) * f1_.x; a0.w += (cf) * f1_.y;                            \
        a1.x += (cf) * f2_.x; a1.y += (cf) * f2_.y;                            \
        a1.z += (cf) * f3_.x; a1.w += (cf) * f3_.y;                            \
    }
    // self-loop term
    {
        float4 rs = g16[(size_t)n * T + q];
        ACC8(rs, di * di);
    }
    int p = beg;
    for (; p + 4 <= end; p += 4) {
        int2 e0 = pairs[p], e1 = pairs[p + 1], e2 = pairs[p + 2], e3 = pairs[p + 3];
        float4 r0 = g16[(size_t)e0.x * T + q];
        float4 r1 = g16[(size_t)e1.x * T + q];
        float4 r2 = g16[(size_t)e2.x * T + q];
        float4 r3 = g16[(size_t)e3.x * T + q];
        ACC8(r0, __int_as_float(e0.y));
        ACC8(r1, __int_as_float(e1.y));
        ACC8(r2, __int_as_float(e2.y));
        ACC8(r3, __int_as_float(e3.y));
    }
    for (; p < end; ++p) {
        int2 pr = pairs[p];
        float4 r = g16[(size_t)pr.x * T + q];
        ACC8(r, __int_as_float(pr.y));
    }
#undef ACC8
    float4 bb0 = *(const float4*)(b + q * 8);
    float4 bb1 = *(const float4*)(b + q * 8 + 4);
    a0.x += bb0.x; a0.y += bb0.y; a0.z += bb0.z; a0.w += bb0.w;
    a1.x += bb1.x; a1.y += bb1.y; a1.z += bb1.z; a1.w += bb1.w;
    size_t nb = (size_t)n * C + q * 2;
    if (MODE == 0) {
        a0.x = fmaxf(a0.x, 0.f); a0.y = fmaxf(a0.y, 0.f);
        a0.z = fmaxf(a0.z, 0.f); a0.w = fmaxf(a0.w, 0.f);
        a1.x = fmaxf(a1.x, 0.f); a1.y = fmaxf(a1.y, 0.f);
        a1.z = fmaxf(a1.z, 0.f); a1.w = fmaxf(a1.w, 0.f);
        ((float4*)outp)[nb] = a0;
        ((float4*)outp)[nb + 1] = a1;
    } else {
        ((float4*)outp)[nb] = a0;
        ((float4*)outp)[nb + 1] = a1;
        ((float4*)outp)[(size_t)NN * C + nb] = a0;      // logstd = mu
        ((float4*)outp)[(size_t)NN * C + nb + 1] = a1;
    }
}

extern "C" void kernel_launch(void* const* d_in, const int* in_sizes, int n_in,
                              void* d_out, int out_size, void* d_ws, size_t ws_size,
                              hipStream_t stream) {
    const float* x  = (const float*)d_in[0];
    const int*   ei = (const int*)d_in[1];  // [2, NE] int32
    const float* W0 = (const float*)d_in[2];
    const float* b0 = (const float*)d_in[3];
    const float* W1 = (const float*)d_in[4];
    const float* b1 = (const float*)d_in[5];
    const float* W2 = (const float*)d_in[6];
    const float* b2 = (const float*)d_in[7];
    float* out = (float*)d_out;

    // ws: [cnt 51200][rowptr 51264][bsum 64][dinv 51200f]
    //     [pairs NE int2][bufA NN*96 f][bufH16 NN*96 half]
    int*    cnt    = (int*)d_ws;
    int*    rowptr = cnt + 51200;
    int*    bsum   = rowptr + 51264;
    float*  dinv   = (float*)(bsum + 64);
    int2*   pairs  = (int2*)(dinv + 51200);
    float*  bufA   = (float*)(pairs + NE);
    __half* bufH16 = (__half*)(bufA + (size_t)NN * 96);

    const int* src = ei;
    const int* dst = ei + NE;

    // CSR build (graph constant across layers; rebuilt identically every call)
    hipMemsetAsync(cnt, 0, NN * sizeof(int), stream);
    k_count<<<NE / 256, 256, 0, stream>>>(dst, cnt);
    k_scanA<<<NB, 1024, 0, stream>>>(cnt, rowptr, bsum, dinv);
    k_scanC<<<(NN + 255) / 256, 256, 0, stream>>>(rowptr, bsum);
    k_fill<<<NE / 256, 256, 0, stream>>>(src, dst, dinv, rowptr, pairs);

    // agg grids: 96-wide -> 12 thr/node; 64-wide -> 8 thr/node (192-thr blocks)
    constexpr int AG96 = (NN * 12 + 191) / 192;  // 3125
    constexpr int AG64 = (NN * 8 + 191) / 192;   // 2084
    constexpr int GEMMG = (NN + 63) / 64;        // 782

    // layer 0: x -> bufA (relu)
    k_gemm<96, 96><<<GEMMG, 192, 0, stream>>>(x, W0, bufH16);
    k_agg<96, 0><<<AG96, 192, 0, stream>>>(bufH16, rowptr, pairs, dinv, b0, bufA);
    // layer 1: bufA -> bufA (relu)
    k_gemm<96, 96><<<GEMMG, 192, 0, stream>>>(bufA, W1, bufH16);
    k_agg<96, 0><<<AG96, 192, 0, stream>>>(bufH16, rowptr, pairs, dinv, b1, bufA);
    // layer 2: bufA -> out (mu, mirrored to logstd)
    k_gemm<96, 64><<<GEMMG, 128, 0, stream>>>(bufA, W2, bufH16);
    k_agg<64, 1><<<AG64, 192, 0, stream>>>(bufH16, rowptr, pairs, dinv, b2, out);
}